// Round 1
// baseline (1298.899 us; speedup 1.0000x reference)
//
#include <hip/hip_runtime.h>

typedef unsigned short u16;
typedef unsigned int   u32;
typedef short  short8  __attribute__((ext_vector_type(8)));
typedef __bf16 bf16x8  __attribute__((ext_vector_type(8)));
typedef float  f32x4   __attribute__((ext_vector_type(4)));

#define POWER_ITERS 48
#define L_SEQ 16384

// ---------- helpers ----------
__device__ __forceinline__ u16 f2bf(float f){
  u32 u = __float_as_uint(f);
  u32 r = (u + 0x7FFFu + ((u >> 16) & 1u)) >> 16;   // RNE
  return (u16)r;
}
__device__ __forceinline__ float bf2f(u16 h){ return __uint_as_float(((u32)h) << 16); }

__device__ __forceinline__ f32x4 mfma_bf16(short8 a, short8 b, f32x4 c){
  return __builtin_amdgcn_mfma_f32_16x16x32_bf16(
      __builtin_bit_cast(bf16x8, a), __builtin_bit_cast(bf16x8, b), c, 0, 0, 0);
}

// swizzled LDS address (u16 units) of element [row][k] of a 64x64 matrix.
// 16B-chunk XOR swizzle: chunk (k>>3) stored at position (k>>3)^(row&7).
__device__ __forceinline__ int swz(int row, int k){
  return row*64 + ((((k >> 3) ^ (row & 7)) << 3) | (k & 7));
}
// 16B fragment (8 bf16) from swizzled LDS: row, k-chunk k0 (multiple of 8)
__device__ __forceinline__ short8 lds_frag(const u16* P, int row, int k0){
  int pos = (k0 >> 3) ^ (row & 7);
  return *(const short8*)(P + row*64 + pos*8);
}
// 16B fragment from row-major global matrix
__device__ __forceinline__ short8 g_frag(const u16* __restrict__ M, int row, int k0){
  return *(const short8*)(M + row*64 + k0);
}

// write C/D regs (matrix X, C-layout) as X^T into swizzled LDS (bf16).
// lane holds X(r,c): c = j*16 + (lane&15), r = i*16 + (lane>>4)*4 + t
__device__ __forceinline__ void write_CT_lds(u16* Pt, int lane, const f32x4 (&C)[4][4]){
  const int m16 = lane & 15, q = lane >> 4;
#pragma unroll
  for(int i = 0; i < 4; i++){
    const int r0 = i*16 + q*4;
#pragma unroll
    for(int j = 0; j < 4; j++){
      const int c = j*16 + m16;
      const int addr = c*64 + ((((r0 >> 3) ^ (c & 7)) << 3) | (r0 & 7));
      u32 lo = (u32)f2bf(C[i][j][0]) | ((u32)f2bf(C[i][j][1]) << 16);
      u32 hi = (u32)f2bf(C[i][j][2]) | ((u32)f2bf(C[i][j][3]) << 16);
      *(uint2*)(Pt + addr) = make_uint2(lo, hi);
    }
  }
}

// one chain step: C = A (global, row-major) * P (LDS as P^T swizzled); writes P'^T back in place.
__device__ __forceinline__ void chain_step(const u16* __restrict__ Ag, u16* Pt, int lane,
                                           f32x4 (&C)[4][4]){
  const int m16 = lane & 15, q = lane >> 4;
  short8 Af[2][4], Bf[2][4];
#pragma unroll
  for(int ks = 0; ks < 2; ks++){
    const int k0 = ks*32 + q*8;
#pragma unroll
    for(int t = 0; t < 4; t++){
      Af[ks][t] = g_frag(Ag, t*16 + m16, k0);
      Bf[ks][t] = lds_frag(Pt, t*16 + m16, k0);
    }
  }
#pragma unroll
  for(int i = 0; i < 4; i++)
#pragma unroll
    for(int j = 0; j < 4; j++)
      C[i][j] = f32x4{0.f, 0.f, 0.f, 0.f};
#pragma unroll
  for(int ks = 0; ks < 2; ks++)
#pragma unroll
    for(int i = 0; i < 4; i++)
#pragma unroll
      for(int j = 0; j < 4; j++)
        C[i][j] = mfma_bf16(Af[ks][i], Bf[ks][j], C[i][j]);
  write_CT_lds(Pt, lane, C);   // all Pt reads already in regs -> in-place safe
}

// init: P = N (global row-major) -> store P^T into swizzled LDS
__device__ __forceinline__ void load_Pt_transpose(const u16* __restrict__ N, u16* Pt, int lane){
#pragma unroll
  for(int g = 0; g < 8; g++){
    short8 v = *(const short8*)(N + lane*64 + g*8);
#pragma unroll
    for(int t = 0; t < 8; t++){
      int k = g*8 + t;
      Pt[swz(k, lane)] = (u16)v[t];   // P^T[k][lane] = N[lane][k]
    }
  }
}

// chain of chain_len matrices -> one normalized node (bf16, row-major) + log2-scale into S_acc
__device__ void run_chain(const u16* __restrict__ mats, const int* __restrict__ seq,
                          int node, int chain_len, u16* Pt, u16* __restrict__ outp,
                          int* __restrict__ S_acc, int lane){
  int sv = 0;
  if(seq && lane < chain_len) sv = seq[node*chain_len + lane];
  int idx0 = seq ? __shfl(sv, 0, 64) : node*chain_len;
  load_Pt_transpose(mats + (size_t)idx0*4096, Pt, lane);
  f32x4 C[4][4];
  for(int j = 1; j < chain_len; j++){
    int idx = seq ? __shfl(sv, j, 64) : node*chain_len + j;
    chain_step(mats + (size_t)idx*4096, Pt, lane, C);
  }
  // epilogue: normalize by power of 2, store row-major bf16, accumulate exponent
  float mx = 0.f;
#pragma unroll
  for(int i = 0; i < 4; i++)
#pragma unroll
    for(int j = 0; j < 4; j++)
#pragma unroll
      for(int t = 0; t < 4; t++) mx = fmaxf(mx, C[i][j][t]);   // entries all positive
  for(int off = 32; off; off >>= 1) mx = fmaxf(mx, __shfl_xor(mx, off, 64));
  int e; (void)frexpf(mx, &e);            // mx = m * 2^e, m in [0.5,1)
  float s = ldexpf(1.f, -e);              // exact
  const int m16 = lane & 15, q = lane >> 4;
#pragma unroll
  for(int i = 0; i < 4; i++)
#pragma unroll
    for(int j = 0; j < 4; j++)
#pragma unroll
      for(int t = 0; t < 4; t++)
        outp[(i*16 + q*4 + t)*64 + j*16 + m16] = f2bf(C[i][j][t] * s);
  if(lane == 0) atomicAdd(S_acc, e);
}

// ---------- phase A: power iteration (one block per direction) ----------
// smem layout (bytes): [0,8192) rho bf16 swizzled | [8192,40960) T zones (4 x 8KB) |
//                      [40960,57344) accum f32    | [57344,57348) mu
__device__ void power_iter(const u16* __restrict__ Kdir, float* __restrict__ rho_out,
                           char* smem, int iters){
  u16*   rho   = (u16*)smem;
  float* accum = (float*)(smem + 40960);
  float* mup   = (float*)(smem + 57344);
  const int tid = threadIdx.x, lane = tid & 63, wave = tid >> 6;
  u16* Tw = (u16*)(smem + 8192) + wave*4096;
  const int m16 = lane & 15, q = lane >> 4;

  for(int c = 0; c < 16; c++){
    int e = tid*16 + c; int m = e >> 6, k = e & 63;
    rho[swz(m, k)] = (m == k) ? f2bf(1.f/64.f) : (u16)0;
    accum[e] = 0.f;
  }
  __syncthreads();

  for(int it = 0; it < iters; it++){
    short8 Ar[2][4];
#pragma unroll
    for(int ks = 0; ks < 2; ks++)
#pragma unroll
      for(int t = 0; t < 4; t++)
        Ar[ks][t] = lds_frag(rho, t*16 + m16, ks*32 + q*8);

    f32x4 C2[4][4];
#pragma unroll
    for(int i = 0; i < 4; i++)
#pragma unroll
      for(int j = 0; j < 4; j++) C2[i][j] = f32x4{0.f,0.f,0.f,0.f};

    for(int rep = 0; rep < 2; rep++){
      const u16* Kw = Kdir + (size_t)(wave + rep*4)*4096;
      short8 Kf[2][4];
#pragma unroll
      for(int ks = 0; ks < 2; ks++)
#pragma unroll
        for(int t = 0; t < 4; t++)
          Kf[ks][t] = g_frag(Kw, t*16 + m16, ks*32 + q*8);
      // stage 1: C1 = rho * Kw^T   (B-frag of Kw^T = rows of Kw)
      f32x4 C1[4][4];
#pragma unroll
      for(int i = 0; i < 4; i++)
#pragma unroll
        for(int j = 0; j < 4; j++) C1[i][j] = f32x4{0.f,0.f,0.f,0.f};
#pragma unroll
      for(int ks = 0; ks < 2; ks++)
#pragma unroll
        for(int i = 0; i < 4; i++)
#pragma unroll
          for(int j = 0; j < 4; j++)
            C1[i][j] = mfma_bf16(Ar[ks][i], Kf[ks][j], C1[i][j]);
      write_CT_lds(Tw, lane, C1);          // Tw = (rho*Kw^T)^T = Kw*rho, row-major
      // stage 2: C2 += Kw * (Kw*rho)^T = Kw*rho*Kw^T
      short8 Bt[2][4];
#pragma unroll
      for(int ks = 0; ks < 2; ks++)
#pragma unroll
        for(int t = 0; t < 4; t++)
          Bt[ks][t] = lds_frag(Tw, t*16 + m16, ks*32 + q*8);
#pragma unroll
      for(int ks = 0; ks < 2; ks++)
#pragma unroll
        for(int i = 0; i < 4; i++)
#pragma unroll
          for(int j = 0; j < 4; j++)
            C2[i][j] = mfma_bf16(Kf[ks][i], Bt[ks][j], C2[i][j]);
    }
#pragma unroll
    for(int i = 0; i < 4; i++)
#pragma unroll
      for(int j = 0; j < 4; j++)
#pragma unroll
        for(int t = 0; t < 4; t++)
          atomicAdd(&accum[(i*16 + q*4 + t)*64 + j*16 + m16], C2[i][j][t]);
    __syncthreads();
    if(wave == 0){
      float v = accum[lane*65];
      for(int off = 32; off; off >>= 1) v += __shfl_xor(v, off, 64);
      if(lane == 0) *mup = v;
    }
    __syncthreads();
    float inv = 1.f / (*mup);
    bool last = (it == iters - 1);
    for(int c = 0; c < 16; c++){
      int e = tid*16 + c; float v = accum[e] * inv;
      int m = e >> 6, k = e & 63;
      rho[swz(m, k)] = f2bf(v);
      accum[e] = 0.f;
      if(last) rho_out[e] = v;
    }
    __syncthreads();
  }
}

// ---------- kernels ----------
__global__ void k_setup(const float* __restrict__ K, u16* __restrict__ Kbf,
                        u16* __restrict__ KTbf, int* S_acc, float* mu_acc){
  int tid = blockIdx.x*256 + threadIdx.x;
  if(tid < 32768){
    float f = K[tid];
    u16 h = f2bf(f);
    Kbf[tid] = h;
    int a = tid >> 12, r = (tid >> 6) & 63, c = tid & 63;
    KTbf[(a << 12) + (c << 6) + r] = h;
  }
  if(tid == 0){ *S_acc = 0; *mu_acc = 0.f; }
}

// blocks 0,1: power iteration (right/left). blocks 2..257: tree level 1 (1024 nodes of chain 16).
__global__ __launch_bounds__(256) void k_main(const u16* __restrict__ Kbf, const u16* __restrict__ KTbf,
                                              const int* __restrict__ seq,
                                              float* __restrict__ rho_r, float* __restrict__ rho_l,
                                              u16* __restrict__ N1, int* __restrict__ S_acc){
  __shared__ __align__(16) char smem[57352];
  int b = blockIdx.x;
  if(b < 2){
    power_iter(b == 0 ? Kbf : KTbf, b == 0 ? rho_r : rho_l, smem, POWER_ITERS);
  } else {
    int lane = threadIdx.x & 63, wave = threadIdx.x >> 6;
    int node = (b - 2)*4 + wave;
    u16* Pt = (u16*)smem + wave*4096;
    run_chain(Kbf, seq, node, 16, Pt, N1 + (size_t)node*4096, S_acc, lane);
  }
}

__global__ __launch_bounds__(256) void k_chain(const u16* __restrict__ mats, int nodes_total,
                                               int chain_len, u16* __restrict__ outp,
                                               int* __restrict__ S_acc){
  __shared__ __align__(16) u16 Pt4[4][4096];
  int lane = threadIdx.x & 63, wave = threadIdx.x >> 6;
  int node = blockIdx.x*4 + wave;
  if(node >= nodes_total) return;
  run_chain(mats, nullptr, node, chain_len, Pt4[wave], outp + (size_t)node*4096, S_acc, lane);
}

// lambda = tr(sum_a K_a^T rho_l K_a) in fp32 from original kraus (Rayleigh quotient)
__global__ void k_rayleigh(const float* __restrict__ K, const float* __restrict__ rho_l,
                           float* __restrict__ mu_acc){
  int lane = threadIdx.x & 63, wave = threadIdx.x >> 6;
  int wid = blockIdx.x*4 + wave;                 // 0..127
  float part = 0.f;
  for(int p = 0; p < 4; p++){
    int gp = wid*4 + p;                          // 0..511 = (a,i)
    int a = gp >> 6, i = gp & 63;
    float ck = K[a*4096 + lane*64 + i];          // column i of K_a, element lane
    float t = 0.f;
    for(int m = 0; m < 64; m++){
      float cm = __shfl(ck, m, 64);
      t += rho_l[lane*64 + m] * cm;
    }
    float v = ck * t;
    for(int off = 32; off; off >>= 1) v += __shfl_xor(v, off, 64);
    part += v;                                   // full q on every lane after reduce
  }
  if(lane == 0) atomicAdd(mu_acc, part);
}

__global__ __launch_bounds__(256) void k_final(const u16* __restrict__ Mt,
                                               const float* __restrict__ rho_r,
                                               const float* __restrict__ rho_l,
                                               const float* __restrict__ mu_p,
                                               const int* __restrict__ S_p,
                                               float* __restrict__ outp){
  __shared__ float Ml[4096], Rr[4096], U[4096];
  __shared__ float red[4];
  int tid = threadIdx.x;
  for(int e = tid; e < 4096; e += 256){ Ml[e] = bf2f(Mt[e]); Rr[e] = rho_r[e]; }
  __syncthreads();
  int r = tid >> 2, cq = tid & 3;
  for(int c = cq*16; c < cq*16 + 16; c++){
    float s = 0.f;
    for(int k = 0; k < 64; k++) s += Ml[r*64 + k] * Rr[k*64 + c];
    U[r*64 + c] = s;                 // U = M * rho_r
  }
  __syncthreads();
  float part = 0.f;
  for(int c = cq*16; c < cq*16 + 16; c++){
    float w = 0.f;
    for(int k = 0; k < 64; k++) w += U[r*64 + k] * Ml[c*64 + k];  // (M rho_r M^T)[r][c]
    part += w * rho_l[c*64 + r];
  }
  int lane = tid & 63, wave = tid >> 6;
  for(int off = 32; off; off >>= 1) part += __shfl_xor(part, off, 64);
  if(lane == 0) red[wave] = part;
  __syncthreads();
  if(tid == 0){
    double t1 = (double)red[0] + red[1] + red[2] + red[3];
    double lam = (double)(*mu_p);
    double S   = (double)(*S_p);
    double logp = 16384.0*log2(lam) - 2.0*S - log2(t1);
    outp[0] = (float)logp;
  }
}

// ---------- launch ----------
extern "C" void kernel_launch(void* const* d_in, const int* in_sizes, int n_in,
                              void* d_out, int out_size, void* d_ws, size_t ws_size,
                              hipStream_t stream) {
  const float* K  = (const float*)d_in[0];   // (8,64,64) fp32
  const int* seq  = (const int*)d_in[1];     // (16384,) int32
  char* ws = (char*)d_ws;
  // ws layout (bytes), ~8.7 MB total
  u16*   Kbf    = (u16*)(ws);                  // 65536
  u16*   KTbf   = (u16*)(ws + 65536);          // 65536
  float* rho_r  = (float*)(ws + 131072);       // 16384
  float* rho_l  = (float*)(ws + 147456);       // 16384
  int*   S_acc  = (int*)(ws + 163840);
  float* mu_acc = (float*)(ws + 163844);
  u16*   N1     = (u16*)(ws + 164352);         // 1024 * 8KB = 8388608
  u16*   N2     = (u16*)(ws + 8552960);        // 64 * 8KB
  u16*   N3     = (u16*)(ws + 9077248);        // 4 * 8KB
  u16*   N4     = (u16*)(ws + 9110016);        // 8KB

  k_setup   <<<128, 256, 0, stream>>>(K, Kbf, KTbf, S_acc, mu_acc);
  k_main    <<<258, 256, 0, stream>>>(Kbf, KTbf, seq, rho_r, rho_l, N1, S_acc);
  k_chain   <<<16,  256, 0, stream>>>(N1, 64, 16, N2, S_acc);
  k_rayleigh<<<32,  256, 0, stream>>>(K, rho_l, mu_acc);
  k_chain   <<<1,   256, 0, stream>>>(N2, 4, 16, N3, S_acc);
  k_chain   <<<1,   256, 0, stream>>>(N3, 1, 4, N4, S_acc);
  k_final   <<<1,   256, 0, stream>>>(N4, rho_r, rho_l, mu_acc, S_acc, (float*)d_out);
}

// Round 2
// 208.191 us; speedup vs baseline: 6.2390x; 6.2390x over previous
//
#include <hip/hip_runtime.h>

typedef unsigned short u16;
typedef unsigned int   u32;
typedef short  short8  __attribute__((ext_vector_type(8)));
typedef __bf16 bf16x8  __attribute__((ext_vector_type(8)));
typedef float  f32x4   __attribute__((ext_vector_type(4)));

#define POWER_ITERS 16

// ---------- helpers ----------
__device__ __forceinline__ u16 f2bf(float f){
  u32 u = __float_as_uint(f);
  u32 r = (u + 0x7FFFu + ((u >> 16) & 1u)) >> 16;   // RNE
  return (u16)r;
}
__device__ __forceinline__ float bf2f(u16 h){ return __uint_as_float(((u32)h) << 16); }

__device__ __forceinline__ f32x4 mfma_bf16(short8 a, short8 b, f32x4 c){
  return __builtin_amdgcn_mfma_f32_16x16x32_bf16(
      __builtin_bit_cast(bf16x8, a), __builtin_bit_cast(bf16x8, b), c, 0, 0, 0);
}

// swizzled LDS address (u16 units) of element [row][k] of a 64x64 matrix.
__device__ __forceinline__ int swz(int row, int k){
  return row*64 + ((((k >> 3) ^ (row & 7)) << 3) | (k & 7));
}
__device__ __forceinline__ short8 lds_frag(const u16* P, int row, int k0){
  int pos = (k0 >> 3) ^ (row & 7);
  return *(const short8*)(P + row*64 + pos*8);
}
__device__ __forceinline__ short8 g_frag(const u16* __restrict__ M, int row, int k0){
  return *(const short8*)(M + row*64 + k0);
}

// write C/D regs (matrix X, C-layout) as X^T into swizzled LDS (bf16), scaled.
__device__ __forceinline__ void write_CT_lds_s(u16* Pt, int lane, const f32x4 (&C)[4][4], float s){
  const int m16 = lane & 15, q = lane >> 4;
#pragma unroll
  for(int i = 0; i < 4; i++){
    const int r0 = i*16 + q*4;
#pragma unroll
    for(int j = 0; j < 4; j++){
      const int c = j*16 + m16;
      const int addr = c*64 + ((((r0 >> 3) ^ (c & 7)) << 3) | (r0 & 7));
      u32 lo = (u32)f2bf(C[i][j][0]*s) | ((u32)f2bf(C[i][j][1]*s) << 16);
      u32 hi = (u32)f2bf(C[i][j][2]*s) | ((u32)f2bf(C[i][j][3]*s) << 16);
      *(uint2*)(Pt + addr) = make_uint2(lo, hi);
    }
  }
}
__device__ __forceinline__ void write_CT_lds(u16* Pt, int lane, const f32x4 (&C)[4][4]){
  write_CT_lds_s(Pt, lane, C, 1.f);
}

// one chain step: C = A (global, row-major) * P (LDS as P^T swizzled); writes P'^T back in place.
__device__ __forceinline__ void chain_step(const u16* __restrict__ Ag, u16* Pt, int lane,
                                           f32x4 (&C)[4][4]){
  const int m16 = lane & 15, q = lane >> 4;
  short8 Af[2][4], Bf[2][4];
#pragma unroll
  for(int ks = 0; ks < 2; ks++){
    const int k0 = ks*32 + q*8;
#pragma unroll
    for(int t = 0; t < 4; t++){
      Af[ks][t] = g_frag(Ag, t*16 + m16, k0);
      Bf[ks][t] = lds_frag(Pt, t*16 + m16, k0);
    }
  }
#pragma unroll
  for(int i = 0; i < 4; i++)
#pragma unroll
    for(int j = 0; j < 4; j++)
      C[i][j] = f32x4{0.f, 0.f, 0.f, 0.f};
#pragma unroll
  for(int ks = 0; ks < 2; ks++)
#pragma unroll
    for(int i = 0; i < 4; i++)
#pragma unroll
      for(int j = 0; j < 4; j++)
        C[i][j] = mfma_bf16(Af[ks][i], Bf[ks][j], C[i][j]);
  write_CT_lds(Pt, lane, C);   // all Pt reads already in regs -> in-place safe
}

// same but A comes from an LDS zone holding A row-major swizzled
__device__ __forceinline__ void chain_step_L(const u16* Az, u16* Pt, int lane, f32x4 (&C)[4][4]){
  const int m16 = lane & 15, q = lane >> 4;
  short8 Af[2][4], Bf[2][4];
#pragma unroll
  for(int ks = 0; ks < 2; ks++){
    const int k0 = ks*32 + q*8;
#pragma unroll
    for(int t = 0; t < 4; t++){
      Af[ks][t] = lds_frag(Az, t*16 + m16, k0);
      Bf[ks][t] = lds_frag(Pt, t*16 + m16, k0);
    }
  }
#pragma unroll
  for(int i = 0; i < 4; i++)
#pragma unroll
    for(int j = 0; j < 4; j++)
      C[i][j] = f32x4{0.f, 0.f, 0.f, 0.f};
#pragma unroll
  for(int ks = 0; ks < 2; ks++)
#pragma unroll
    for(int i = 0; i < 4; i++)
#pragma unroll
      for(int j = 0; j < 4; j++)
        C[i][j] = mfma_bf16(Af[ks][i], Bf[ks][j], C[i][j]);
  write_CT_lds(Pt, lane, C);
}

// init: P = N (global row-major) -> store P^T into swizzled LDS
__device__ __forceinline__ void load_Pt_transpose(const u16* __restrict__ N, u16* Pt, int lane){
#pragma unroll
  for(int g = 0; g < 8; g++){
    short8 v = *(const short8*)(N + lane*64 + g*8);
#pragma unroll
    for(int t = 0; t < 8; t++){
      int k = g*8 + t;
      Pt[swz(k, lane)] = (u16)v[t];   // P^T[k][lane] = N[lane][k]
    }
  }
}

__device__ __forceinline__ float wave_max(float mx){
  for(int off = 32; off; off >>= 1) mx = fmaxf(mx, __shfl_xor(mx, off, 64));
  return mx;
}

// chain of chain_len matrices -> one normalized node (bf16, row-major GLOBAL) + log2-scale into S_acc
__device__ void run_chain(const u16* __restrict__ mats, const int* __restrict__ seq,
                          int node, int chain_len, u16* Pt, u16* __restrict__ outp,
                          int* __restrict__ S_acc, int lane){
  int sv = 0;
  if(seq && lane < chain_len) sv = seq[node*chain_len + lane];
  int idx0 = seq ? __shfl(sv, 0, 64) : node*chain_len;
  load_Pt_transpose(mats + (size_t)idx0*4096, Pt, lane);
  f32x4 C[4][4];
  for(int j = 1; j < chain_len; j++){
    int idx = seq ? __shfl(sv, j, 64) : node*chain_len + j;
    chain_step(mats + (size_t)idx*4096, Pt, lane, C);
  }
  float mx = 0.f;
#pragma unroll
  for(int i = 0; i < 4; i++)
#pragma unroll
    for(int j = 0; j < 4; j++)
#pragma unroll
      for(int t = 0; t < 4; t++) mx = fmaxf(mx, C[i][j][t]);   // entries all positive
  mx = wave_max(mx);
  int e; (void)frexpf(mx, &e);
  float s = ldexpf(1.f, -e);
  const int m16 = lane & 15, q = lane >> 4;
#pragma unroll
  for(int i = 0; i < 4; i++)
#pragma unroll
    for(int j = 0; j < 4; j++)
#pragma unroll
      for(int t = 0; t < 4; t++)
        outp[(i*16 + q*4 + t)*64 + j*16 + m16] = f2bf(C[i][j][t] * s);
  if(lane == 0) atomicAdd(S_acc, e);
}

// ---------- power iteration: 8 waves, one Kraus op per wave, K frags register-resident ----------
// smem (bytes): zones 8x8KB at [0,64K) | rho bf16 swizzled [64K,72K) | red f32[8] at 72K
__device__ void power_iter(const u16* __restrict__ Kdir, float* __restrict__ rho_out,
                           char* smem, int iters){
  u16*   zones = (u16*)smem;
  u16*   rho   = (u16*)(smem + 65536);
  float* red   = (float*)(smem + 73728);
  const int tid = threadIdx.x, lane = tid & 63, wave = tid >> 6;
  u16* zw = zones + wave*4096;
  const int m16 = lane & 15, q = lane >> 4;

  // K fragments held in registers for the whole loop (8 frags x 16B = 32 VGPRs)
  short8 Kf[2][4];
  {
    const u16* Kw = Kdir + (size_t)wave*4096;
#pragma unroll
    for(int ks = 0; ks < 2; ks++)
#pragma unroll
      for(int t = 0; t < 4; t++)
        Kf[ks][t] = g_frag(Kw, t*16 + m16, ks*32 + q*8);
  }

  // rho = I/64, one 16B store per thread (512 threads x 8 elems = 4096)
  const int row = tid >> 3, k0 = (tid & 7) * 8;
  {
    short8 b;
#pragma unroll
    for(int j = 0; j < 8; j++) b[j] = (row == k0 + j) ? (short)f2bf(1.f/64.f) : (short)0;
    *(short8*)(rho + row*64 + (((k0 >> 3) ^ (row & 7)) << 3)) = b;
  }
  __syncthreads();

  for(int it = 0; it < iters; it++){
    // stage 1: C = rho * Kw^T
    short8 Ar[2][4];
#pragma unroll
    for(int ks = 0; ks < 2; ks++)
#pragma unroll
      for(int t = 0; t < 4; t++)
        Ar[ks][t] = lds_frag(rho, t*16 + m16, ks*32 + q*8);
    f32x4 C[4][4];
#pragma unroll
    for(int i = 0; i < 4; i++)
#pragma unroll
      for(int j = 0; j < 4; j++) C[i][j] = f32x4{0.f,0.f,0.f,0.f};
#pragma unroll
    for(int ks = 0; ks < 2; ks++)
#pragma unroll
      for(int i = 0; i < 4; i++)
#pragma unroll
        for(int j = 0; j < 4; j++)
          C[i][j] = mfma_bf16(Ar[ks][i], Kf[ks][j], C[i][j]);
    write_CT_lds(zw, lane, C);          // zw = (rho*Kw^T)^T = Kw*rho (rho symmetric)

    // stage 2: C = Kw * (Kw*rho)^T = Kw*rho*Kw^T
    short8 Bt[2][4];
#pragma unroll
    for(int ks = 0; ks < 2; ks++)
#pragma unroll
      for(int t = 0; t < 4; t++)
        Bt[ks][t] = lds_frag(zw, t*16 + m16, ks*32 + q*8);
#pragma unroll
    for(int i = 0; i < 4; i++)
#pragma unroll
      for(int j = 0; j < 4; j++) C[i][j] = f32x4{0.f,0.f,0.f,0.f};
#pragma unroll
    for(int ks = 0; ks < 2; ks++)
#pragma unroll
      for(int i = 0; i < 4; i++)
#pragma unroll
        for(int j = 0; j < 4; j++)
          C[i][j] = mfma_bf16(Kf[ks][i], Bt[ks][j], C[i][j]);
    write_CT_lds(zw, lane, C);          // zone_w = wave's Kraus term (Bt in regs -> safe)
    __syncthreads();

    // reduce 8 zones: each thread owns 8 contiguous elems of one swizzled row
    float v[8];
#pragma unroll
    for(int j = 0; j < 8; j++) v[j] = 0.f;
#pragma unroll
    for(int z = 0; z < 8; z++){
      short8 f = lds_frag(zones + z*4096, row, k0);
#pragma unroll
      for(int j = 0; j < 8; j++) v[j] += bf2f((u16)f[j]);
    }
    float pd = 0.f;
    if(k0 <= row && row < k0 + 8) pd = v[row - k0];   // trace partial
    for(int off = 32; off; off >>= 1) pd += __shfl_xor(pd, off, 64);
    if(lane == 0) red[wave] = pd;
    __syncthreads();
    float mu = 0.f;
#pragma unroll
    for(int w = 0; w < 8; w++) mu += red[w];
    float inv = 1.f / mu;
    short8 b;
#pragma unroll
    for(int j = 0; j < 8; j++) b[j] = (short)f2bf(v[j] * inv);
    *(short8*)(rho + row*64 + (((k0 >> 3) ^ (row & 7)) << 3)) = b;
    if(it == iters - 1){
#pragma unroll
      for(int j = 0; j < 8; j++) rho_out[row*64 + k0 + j] = v[j] * inv;  // symmetric: layout-agnostic
    }
    __syncthreads();
  }
}

// ---------- kernels ----------
__global__ void k_setup(const float* __restrict__ K, u16* __restrict__ Kbf,
                        u16* __restrict__ KTbf, int* S_acc, float* mu_acc){
  int tid = blockIdx.x*256 + threadIdx.x;
  if(tid < 32768){
    float f = K[tid];
    u16 h = f2bf(f);
    Kbf[tid] = h;
    int a = tid >> 12, r = (tid >> 6) & 63, c = tid & 63;
    KTbf[(a << 12) + (c << 6) + r] = h;
  }
  if(tid == 0){ *S_acc = 0; *mu_acc = 0.f; }
}

// blocks 0,1: power iteration (right/left). blocks 2..129: tree level 1 (1024 nodes, 8 chains/block).
__global__ __launch_bounds__(512, 2) void k_main(const u16* __restrict__ Kbf, const u16* __restrict__ KTbf,
                                                 const int* __restrict__ seq,
                                                 float* __restrict__ rho_r, float* __restrict__ rho_l,
                                                 u16* __restrict__ N1, int* __restrict__ S_acc){
  __shared__ __align__(16) char smem[73792];
  int b = blockIdx.x;
  if(b < 2){
    power_iter(b == 0 ? Kbf : KTbf, b == 0 ? rho_r : rho_l, smem, POWER_ITERS);
  } else {
    int lane = threadIdx.x & 63, wave = threadIdx.x >> 6;
    int node = (b - 2)*8 + wave;
    u16* Pt = (u16*)smem + wave*4096;
    run_chain(Kbf, seq, node, 16, Pt, N1 + (size_t)node*4096, S_acc, lane);
  }
}

__global__ __launch_bounds__(256) void k_chain(const u16* __restrict__ mats, int nodes_total,
                                               int chain_len, u16* __restrict__ outp,
                                               int* __restrict__ S_acc){
  __shared__ __align__(16) u16 Pt4[4][4096];
  int lane = threadIdx.x & 63, wave = threadIdx.x >> 6;
  int node = blockIdx.x*4 + wave;
  if(node >= nodes_total) return;
  run_chain(mats, nullptr, node, chain_len, Pt4[wave], outp + (size_t)node*4096, S_acc, lane);
}

// lambda = tr(sum_a K_a^T rho_l K_a) in fp32 from original kraus (Rayleigh quotient)
__global__ void k_rayleigh(const float* __restrict__ K, const float* __restrict__ rho_l,
                           float* __restrict__ mu_acc){
  int lane = threadIdx.x & 63, wave = threadIdx.x >> 6;
  int wid = blockIdx.x*4 + wave;                 // 0..127
  float part = 0.f;
  for(int p = 0; p < 4; p++){
    int gp = wid*4 + p;                          // 0..511 = (a,i)
    int a = gp >> 6, i = gp & 63;
    float ck = K[a*4096 + lane*64 + i];          // column i of K_a, element lane
    float t = 0.f;
    for(int m = 0; m < 64; m++){
      float cm = __shfl(ck, m, 64);
      t += rho_l[lane*64 + m] * cm;
    }
    float v = ck * t;
    for(int off = 32; off; off >>= 1) v += __shfl_xor(v, off, 64);
    part += v;
  }
  if(lane == 0) atomicAdd(mu_acc, part);
}

// merged tail: 64 N2-nodes -> 4 (phase1, LDS-resident) -> M (phase2) -> contraction (phase3)
__global__ __launch_bounds__(256) void k_tail(const u16* __restrict__ N2,
                                              const float* __restrict__ rho_r,
                                              const float* __restrict__ rho_l,
                                              const float* __restrict__ mu_p,
                                              const int* __restrict__ S_p,
                                              float* __restrict__ outp){
  __shared__ __align__(16) u16 zones[5*4096];   // 4 node results + running product
  __shared__ float Ml[4096], Rr[4096], U[4096];
  __shared__ float red[4];
  __shared__ int exps[4];
  const int tid = threadIdx.x, lane = tid & 63, wave = tid >> 6;

  // phase 1: 4 chains of 16 over N2; result stays in zone_w as P_w^T (normalized bf16)
  {
    u16* Pt = zones + wave*4096;
    load_Pt_transpose(N2 + (size_t)(wave*16)*4096, Pt, lane);
    f32x4 C[4][4];
    for(int j = 1; j < 16; j++)
      chain_step(N2 + (size_t)(wave*16 + j)*4096, Pt, lane, C);
    float mx = 0.f;
#pragma unroll
    for(int i = 0; i < 4; i++)
#pragma unroll
      for(int j = 0; j < 4; j++)
#pragma unroll
        for(int t = 0; t < 4; t++) mx = fmaxf(mx, C[i][j][t]);
    mx = wave_max(mx);
    int e; (void)frexpf(mx, &e);
    write_CT_lds_s(Pt, lane, C, ldexpf(1.f, -e));
    if(lane == 0) exps[wave] = e;
  }
  __syncthreads();

  // phase 2 (wave 0): run = Q0*Q1*Q2*Q3 with Q_w = P_w^T  => run = M^T; Pt_run holds run^T = M
  if(wave == 0){
    u16* Pr = zones + 4*4096;
#pragma unroll
    for(int g = 0; g < 8; g++){                 // Pt_run <- Q3^T
      short8 f = lds_frag(zones + 3*4096, lane, g*8);
#pragma unroll
      for(int j = 0; j < 8; j++) Pr[swz(g*8 + j, lane)] = (u16)f[j];
    }
    f32x4 C[4][4];
    chain_step_L(zones + 2*4096, Pr, lane, C);
    chain_step_L(zones + 1*4096, Pr, lane, C);
    chain_step_L(zones + 0*4096, Pr, lane, C);  // no norm needed: entries <= 2^18 in bf16 range
  }
  __syncthreads();

  // phase 3: t1 = tr(M rho_r M^T rho_l)
  for(int e = tid; e < 4096; e += 256){
    int r = e >> 6, c = e & 63;
    Ml[e] = bf2f(zones[4*4096 + swz(r, c)]);
    Rr[e] = rho_r[e];
  }
  __syncthreads();
  int r = tid >> 2, cq = tid & 3;
  for(int c = cq*16; c < cq*16 + 16; c++){
    float s = 0.f;
    for(int k = 0; k < 64; k++) s += Ml[r*64 + k] * Rr[k*64 + c];
    U[r*64 + c] = s;                 // U = M * rho_r
  }
  __syncthreads();
  float part = 0.f;
  for(int c = cq*16; c < cq*16 + 16; c++){
    float w = 0.f;
    for(int k = 0; k < 64; k++) w += U[r*64 + k] * Ml[c*64 + k];  // (M rho_r M^T)[r][c]
    part += w * rho_l[c*64 + r];
  }
  for(int off = 32; off; off >>= 1) part += __shfl_xor(part, off, 64);
  if(lane == 0) red[wave] = part;
  __syncthreads();
  if(tid == 0){
    double t1 = (double)red[0] + red[1] + red[2] + red[3];
    double lam = (double)(*mu_p);
    double S   = (double)(*S_p) + exps[0] + exps[1] + exps[2] + exps[3];
    double logp = 16384.0*log2(lam) - 2.0*S - log2(t1);
    outp[0] = (float)logp;
  }
}

// ---------- launch ----------
extern "C" void kernel_launch(void* const* d_in, const int* in_sizes, int n_in,
                              void* d_out, int out_size, void* d_ws, size_t ws_size,
                              hipStream_t stream) {
  const float* K  = (const float*)d_in[0];   // (8,64,64) fp32
  const int* seq  = (const int*)d_in[1];     // (16384,) int32
  char* ws = (char*)d_ws;
  u16*   Kbf    = (u16*)(ws);                  // 65536
  u16*   KTbf   = (u16*)(ws + 65536);          // 65536
  float* rho_r  = (float*)(ws + 131072);       // 16384
  float* rho_l  = (float*)(ws + 147456);       // 16384
  int*   S_acc  = (int*)(ws + 163840);
  float* mu_acc = (float*)(ws + 163844);
  u16*   N1     = (u16*)(ws + 164352);         // 1024 * 8KB
  u16*   N2     = (u16*)(ws + 8552960);        // 64 * 8KB

  k_setup   <<<128, 256, 0, stream>>>(K, Kbf, KTbf, S_acc, mu_acc);
  k_main    <<<130, 512, 0, stream>>>(Kbf, KTbf, seq, rho_r, rho_l, N1, S_acc);
  k_chain   <<<16,  256, 0, stream>>>(N1, 64, 16, N2, S_acc);
  k_rayleigh<<<32,  256, 0, stream>>>(K, rho_l, mu_acc);
  k_tail    <<<1,   256, 0, stream>>>(N2, rho_r, rho_l, mu_acc, S_acc, (float*)d_out);
}

// Round 3
// 177.876 us; speedup vs baseline: 7.3023x; 1.1704x over previous
//
#include <hip/hip_runtime.h>

typedef unsigned short u16;
typedef unsigned int   u32;
typedef short  short8  __attribute__((ext_vector_type(8)));
typedef __bf16 bf16x8  __attribute__((ext_vector_type(8)));
typedef float  f32x4   __attribute__((ext_vector_type(4)));

#define POWER_ITERS 16

// ---------- helpers ----------
__device__ __forceinline__ u16 f2bf(float f){
  u32 u = __float_as_uint(f);
  u32 r = (u + 0x7FFFu + ((u >> 16) & 1u)) >> 16;   // RNE
  return (u16)r;
}
__device__ __forceinline__ float bf2f(u16 h){ return __uint_as_float(((u32)h) << 16); }

__device__ __forceinline__ f32x4 mfma_bf16(short8 a, short8 b, f32x4 c){
  return __builtin_amdgcn_mfma_f32_16x16x32_bf16(
      __builtin_bit_cast(bf16x8, a), __builtin_bit_cast(bf16x8, b), c, 0, 0, 0);
}

// swizzled LDS address (u16 units) of element [row][k] of a 64x64 matrix.
__device__ __forceinline__ int swz(int row, int k){
  return row*64 + ((((k >> 3) ^ (row & 7)) << 3) | (k & 7));
}
__device__ __forceinline__ short8 lds_frag(const u16* P, int row, int k0){
  int pos = (k0 >> 3) ^ (row & 7);
  return *(const short8*)(P + row*64 + pos*8);
}
__device__ __forceinline__ short8 g_frag(const u16* __restrict__ M, int row, int k0){
  return *(const short8*)(M + row*64 + k0);
}

// write C/D regs (matrix X, C-layout) as X^T into swizzled LDS (bf16), scaled.
__device__ __forceinline__ void write_CT_lds_s(u16* Pt, int lane, const f32x4 (&C)[4][4], float s){
  const int m16 = lane & 15, q = lane >> 4;
#pragma unroll
  for(int i = 0; i < 4; i++){
    const int r0 = i*16 + q*4;
#pragma unroll
    for(int j = 0; j < 4; j++){
      const int c = j*16 + m16;
      const int addr = c*64 + ((((r0 >> 3) ^ (c & 7)) << 3) | (r0 & 7));
      u32 lo = (u32)f2bf(C[i][j][0]*s) | ((u32)f2bf(C[i][j][1]*s) << 16);
      u32 hi = (u32)f2bf(C[i][j][2]*s) | ((u32)f2bf(C[i][j][3]*s) << 16);
      *(uint2*)(Pt + addr) = make_uint2(lo, hi);
    }
  }
}
__device__ __forceinline__ void write_CT_lds(u16* Pt, int lane, const f32x4 (&C)[4][4]){
  write_CT_lds_s(Pt, lane, C, 1.f);
}

// one chain step: C = A (global, row-major) * P (LDS as P^T swizzled); writes P'^T back in place.
__device__ __forceinline__ void chain_step(const u16* __restrict__ Ag, u16* Pt, int lane,
                                           f32x4 (&C)[4][4]){
  const int m16 = lane & 15, q = lane >> 4;
  short8 Af[2][4], Bf[2][4];
#pragma unroll
  for(int ks = 0; ks < 2; ks++){
    const int k0 = ks*32 + q*8;
#pragma unroll
    for(int t = 0; t < 4; t++){
      Af[ks][t] = g_frag(Ag, t*16 + m16, k0);
      Bf[ks][t] = lds_frag(Pt, t*16 + m16, k0);
    }
  }
#pragma unroll
  for(int i = 0; i < 4; i++)
#pragma unroll
    for(int j = 0; j < 4; j++)
      C[i][j] = f32x4{0.f, 0.f, 0.f, 0.f};
#pragma unroll
  for(int ks = 0; ks < 2; ks++)
#pragma unroll
    for(int i = 0; i < 4; i++)
#pragma unroll
      for(int j = 0; j < 4; j++)
        C[i][j] = mfma_bf16(Af[ks][i], Bf[ks][j], C[i][j]);
  write_CT_lds(Pt, lane, C);   // all Pt reads already in regs -> in-place safe
}

// same but A comes from an LDS zone holding A row-major swizzled
__device__ __forceinline__ void chain_step_L(const u16* Az, u16* Pt, int lane, f32x4 (&C)[4][4]){
  const int m16 = lane & 15, q = lane >> 4;
  short8 Af[2][4], Bf[2][4];
#pragma unroll
  for(int ks = 0; ks < 2; ks++){
    const int k0 = ks*32 + q*8;
#pragma unroll
    for(int t = 0; t < 4; t++){
      Af[ks][t] = lds_frag(Az, t*16 + m16, k0);
      Bf[ks][t] = lds_frag(Pt, t*16 + m16, k0);
    }
  }
#pragma unroll
  for(int i = 0; i < 4; i++)
#pragma unroll
    for(int j = 0; j < 4; j++)
      C[i][j] = f32x4{0.f, 0.f, 0.f, 0.f};
#pragma unroll
  for(int ks = 0; ks < 2; ks++)
#pragma unroll
    for(int i = 0; i < 4; i++)
#pragma unroll
      for(int j = 0; j < 4; j++)
        C[i][j] = mfma_bf16(Af[ks][i], Bf[ks][j], C[i][j]);
  write_CT_lds(Pt, lane, C);
}

// init: P = N (global row-major) -> store P^T into swizzled LDS
__device__ __forceinline__ void load_Pt_transpose(const u16* __restrict__ N, u16* Pt, int lane){
#pragma unroll
  for(int g = 0; g < 8; g++){
    short8 v = *(const short8*)(N + lane*64 + g*8);
#pragma unroll
    for(int t = 0; t < 8; t++){
      int k = g*8 + t;
      Pt[swz(k, lane)] = (u16)v[t];   // P^T[k][lane] = N[lane][k]
    }
  }
}

__device__ __forceinline__ float wave_max(float mx){
  for(int off = 32; off; off >>= 1) mx = fmaxf(mx, __shfl_xor(mx, off, 64));
  return mx;
}

// chain of chain_len matrices -> one normalized node (bf16, row-major GLOBAL) + log2-scale into S_acc
__device__ void run_chain(const u16* __restrict__ mats, const int* __restrict__ seq,
                          int node, int chain_len, u16* Pt, u16* __restrict__ outp,
                          int* __restrict__ S_acc, int lane){
  int sv = 0;
  if(seq && lane < chain_len) sv = seq[node*chain_len + lane];
  int idx0 = seq ? __shfl(sv, 0, 64) : node*chain_len;
  load_Pt_transpose(mats + (size_t)idx0*4096, Pt, lane);
  f32x4 C[4][4];
  for(int j = 1; j < chain_len; j++){
    int idx = seq ? __shfl(sv, j, 64) : node*chain_len + j;
    chain_step(mats + (size_t)idx*4096, Pt, lane, C);
  }
  float mx = 0.f;
#pragma unroll
  for(int i = 0; i < 4; i++)
#pragma unroll
    for(int j = 0; j < 4; j++)
#pragma unroll
      for(int t = 0; t < 4; t++) mx = fmaxf(mx, C[i][j][t]);   // entries all positive
  mx = wave_max(mx);
  int e; (void)frexpf(mx, &e);
  float s = ldexpf(1.f, -e);
  const int m16 = lane & 15, q = lane >> 4;
#pragma unroll
  for(int i = 0; i < 4; i++)
#pragma unroll
    for(int j = 0; j < 4; j++)
#pragma unroll
      for(int t = 0; t < 4; t++)
        outp[(i*16 + q*4 + t)*64 + j*16 + m16] = f2bf(C[i][j][t] * s);
  if(lane == 0) atomicAdd(S_acc, e);
}

// ---------- power iteration: 8 waves, one Kraus op per wave, K frags register-resident ----------
__device__ void power_iter(const u16* __restrict__ Kdir, float* __restrict__ rho_out,
                           char* smem, int iters){
  u16*   zones = (u16*)smem;
  u16*   rho   = (u16*)(smem + 65536);
  float* red   = (float*)(smem + 73728);
  const int tid = threadIdx.x, lane = tid & 63, wave = tid >> 6;
  u16* zw = zones + wave*4096;
  const int m16 = lane & 15, q = lane >> 4;

  short8 Kf[2][4];
  {
    const u16* Kw = Kdir + (size_t)wave*4096;
#pragma unroll
    for(int ks = 0; ks < 2; ks++)
#pragma unroll
      for(int t = 0; t < 4; t++)
        Kf[ks][t] = g_frag(Kw, t*16 + m16, ks*32 + q*8);
  }

  const int row = tid >> 3, k0 = (tid & 7) * 8;
  {
    short8 b;
#pragma unroll
    for(int j = 0; j < 8; j++) b[j] = (row == k0 + j) ? (short)f2bf(1.f/64.f) : (short)0;
    *(short8*)(rho + row*64 + (((k0 >> 3) ^ (row & 7)) << 3)) = b;
  }
  __syncthreads();

  for(int it = 0; it < iters; it++){
    short8 Ar[2][4];
#pragma unroll
    for(int ks = 0; ks < 2; ks++)
#pragma unroll
      for(int t = 0; t < 4; t++)
        Ar[ks][t] = lds_frag(rho, t*16 + m16, ks*32 + q*8);
    f32x4 C[4][4];
#pragma unroll
    for(int i = 0; i < 4; i++)
#pragma unroll
      for(int j = 0; j < 4; j++) C[i][j] = f32x4{0.f,0.f,0.f,0.f};
#pragma unroll
    for(int ks = 0; ks < 2; ks++)
#pragma unroll
      for(int i = 0; i < 4; i++)
#pragma unroll
        for(int j = 0; j < 4; j++)
          C[i][j] = mfma_bf16(Ar[ks][i], Kf[ks][j], C[i][j]);
    write_CT_lds(zw, lane, C);          // zw = (rho*Kw^T)^T = Kw*rho (rho symmetric)

    short8 Bt[2][4];
#pragma unroll
    for(int ks = 0; ks < 2; ks++)
#pragma unroll
      for(int t = 0; t < 4; t++)
        Bt[ks][t] = lds_frag(zw, t*16 + m16, ks*32 + q*8);
#pragma unroll
    for(int i = 0; i < 4; i++)
#pragma unroll
      for(int j = 0; j < 4; j++) C[i][j] = f32x4{0.f,0.f,0.f,0.f};
#pragma unroll
    for(int ks = 0; ks < 2; ks++)
#pragma unroll
      for(int i = 0; i < 4; i++)
#pragma unroll
        for(int j = 0; j < 4; j++)
          C[i][j] = mfma_bf16(Kf[ks][i], Bt[ks][j], C[i][j]);
    write_CT_lds(zw, lane, C);
    __syncthreads();

    float v[8];
#pragma unroll
    for(int j = 0; j < 8; j++) v[j] = 0.f;
#pragma unroll
    for(int z = 0; z < 8; z++){
      short8 f = lds_frag(zones + z*4096, row, k0);
#pragma unroll
      for(int j = 0; j < 8; j++) v[j] += bf2f((u16)f[j]);
    }
    float pd = 0.f;
    if(k0 <= row && row < k0 + 8) pd = v[row - k0];
    for(int off = 32; off; off >>= 1) pd += __shfl_xor(pd, off, 64);
    if(lane == 0) red[wave] = pd;
    __syncthreads();
    float mu = 0.f;
#pragma unroll
    for(int w = 0; w < 8; w++) mu += red[w];
    float inv = 1.f / mu;
    short8 b;
#pragma unroll
    for(int j = 0; j < 8; j++) b[j] = (short)f2bf(v[j] * inv);
    *(short8*)(rho + row*64 + (((k0 >> 3) ^ (row & 7)) << 3)) = b;
    if(it == iters - 1){
#pragma unroll
      for(int j = 0; j < 8; j++) rho_out[row*64 + k0 + j] = v[j] * inv;
    }
    __syncthreads();
  }
}

// ---------- kernels ----------
__global__ void k_setup(const float* __restrict__ K, u16* __restrict__ Kbf,
                        u16* __restrict__ KTbf, int* S_acc, float* mu_acc){
  int tid = blockIdx.x*256 + threadIdx.x;
  if(tid < 32768){
    float f = K[tid];
    u16 h = f2bf(f);
    Kbf[tid] = h;
    int a = tid >> 12, r = (tid >> 6) & 63, c = tid & 63;
    KTbf[(a << 12) + (c << 6) + r] = h;
  }
  if(tid == 0){ *S_acc = 0; *mu_acc = 0.f; }
}

// blocks 0,1: power iteration (right/left). blocks 2..129: tree level 1 (1024 nodes, 8 chains/block).
__global__ __launch_bounds__(512, 2) void k_main(const u16* __restrict__ Kbf, const u16* __restrict__ KTbf,
                                                 const int* __restrict__ seq,
                                                 float* __restrict__ rho_r, float* __restrict__ rho_l,
                                                 u16* __restrict__ N1, int* __restrict__ S_acc){
  __shared__ __align__(16) char smem[73792];
  int b = blockIdx.x;
  if(b < 2){
    power_iter(b == 0 ? Kbf : KTbf, b == 0 ? rho_r : rho_l, smem, POWER_ITERS);
  } else {
    int lane = threadIdx.x & 63, wave = threadIdx.x >> 6;
    int node = (b - 2)*8 + wave;
    u16* Pt = (u16*)smem + wave*4096;
    run_chain(Kbf, seq, node, 16, Pt, N1 + (size_t)node*4096, S_acc, lane);
  }
}

// blocks 0..15: tree level 2 (64 nodes of chain 16 over N1).
// blocks 16..47: Rayleigh quotient lambda = tr(sum_a K_a^T rho_l K_a) in fp32.
__global__ __launch_bounds__(256) void k_mid(const u16* __restrict__ N1, u16* __restrict__ N2,
                                             int* __restrict__ S_acc,
                                             const float* __restrict__ K,
                                             const float* __restrict__ rho_l,
                                             float* __restrict__ mu_acc){
  __shared__ __align__(16) u16 Pt4[4][4096];
  int lane = threadIdx.x & 63, wave = threadIdx.x >> 6;
  int b = blockIdx.x;
  if(b < 16){
    int node = b*4 + wave;
    run_chain(N1, nullptr, node, 16, Pt4[wave], N2 + (size_t)node*4096, S_acc, lane);
  } else {
    int wid = (b - 16)*4 + wave;                 // 0..127
    float part = 0.f;
    for(int p = 0; p < 4; p++){
      int gp = wid*4 + p;                        // 0..511 = (a,i)
      int a = gp >> 6, i = gp & 63;
      float ck = K[a*4096 + lane*64 + i];
      float t = 0.f;
      for(int m = 0; m < 64; m++){
        float cm = __shfl(ck, m, 64);
        t += rho_l[lane*64 + m] * cm;
      }
      float v = ck * t;
      for(int off = 32; off; off >>= 1) v += __shfl_xor(v, off, 64);
      part += v;
    }
    if(lane == 0) atomicAdd(mu_acc, part);
  }
}

// merged tail: 64 N2-nodes -> 4 (phase1) -> M (phase2) -> MFMA contraction (phase3)
// zones: 0-3 phase1 results | 4 running product / M | 5 rho_r | 6 rho_l | 7 U^T
__global__ __launch_bounds__(256) void k_tail(const u16* __restrict__ N2,
                                              const float* __restrict__ rho_r,
                                              const float* __restrict__ rho_l,
                                              const float* __restrict__ mu_p,
                                              const int* __restrict__ S_p,
                                              float* __restrict__ outp){
  __shared__ __align__(16) u16 zones[8*4096];
  __shared__ int exps[4];
  const int tid = threadIdx.x, lane = tid & 63, wave = tid >> 6;
  const int m16 = lane & 15, q = lane >> 4;

  // phase 0: rho_r -> zone5, rho_l -> zone6 (bf16 swizzled); 16 elems/thread/matrix
  {
    int row = tid >> 2, c0 = (tid & 3) * 16;
    int p0 = (((c0 >> 3) ^ (row & 7)) << 3);
    int p1 = ((((c0 >> 3) | 1) ^ (row & 7)) << 3);
    const float* pr = rho_r + row*64 + c0;
    const float* pl = rho_l + row*64 + c0;
    short8 s0, s1;
#pragma unroll
    for(int j = 0; j < 8; j++){ s0[j] = (short)f2bf(pr[j]); s1[j] = (short)f2bf(pr[8+j]); }
    *(short8*)(zones + 5*4096 + row*64 + p0) = s0;
    *(short8*)(zones + 5*4096 + row*64 + p1) = s1;
#pragma unroll
    for(int j = 0; j < 8; j++){ s0[j] = (short)f2bf(pl[j]); s1[j] = (short)f2bf(pl[8+j]); }
    *(short8*)(zones + 6*4096 + row*64 + p0) = s0;
    *(short8*)(zones + 6*4096 + row*64 + p1) = s1;
  }

  // phase 1: 4 chains of 16 over N2; result stays in zone_w as P_w^T (normalized bf16)
  {
    u16* Pt = zones + wave*4096;
    load_Pt_transpose(N2 + (size_t)(wave*16)*4096, Pt, lane);
    f32x4 C[4][4];
    for(int j = 1; j < 16; j++)
      chain_step(N2 + (size_t)(wave*16 + j)*4096, Pt, lane, C);
    float mx = 0.f;
#pragma unroll
    for(int i = 0; i < 4; i++)
#pragma unroll
      for(int j = 0; j < 4; j++)
#pragma unroll
        for(int t = 0; t < 4; t++) mx = fmaxf(mx, C[i][j][t]);
    mx = wave_max(mx);
    int e; (void)frexpf(mx, &e);
    write_CT_lds_s(Pt, lane, C, ldexpf(1.f, -e));
    if(lane == 0) exps[wave] = e;
  }
  __syncthreads();

  // phases 2+3 on wave 0 only
  if(wave == 0){
    u16* Pr = zones + 4*4096;
#pragma unroll
    for(int g = 0; g < 8; g++){                 // Pt_run <- Q3^T
      short8 f = lds_frag(zones + 3*4096, lane, g*8);
#pragma unroll
      for(int j = 0; j < 8; j++) Pr[swz(g*8 + j, lane)] = (u16)f[j];
    }
    f32x4 C[4][4];
    chain_step_L(zones + 2*4096, Pr, lane, C);
    chain_step_L(zones + 1*4096, Pr, lane, C);
    chain_step_L(zones + 0*4096, Pr, lane, C);  // Pr now stores M (row-major swizzled)

    // step A: U = M * rho_r  (rho_r symmetric) -> zone7 stores U^T
    short8 Aa[2][4], Bb[2][4];
#pragma unroll
    for(int ks = 0; ks < 2; ks++)
#pragma unroll
      for(int t = 0; t < 4; t++){
        Aa[ks][t] = lds_frag(Pr,              t*16 + m16, ks*32 + q*8);
        Bb[ks][t] = lds_frag(zones + 5*4096,  t*16 + m16, ks*32 + q*8);
      }
#pragma unroll
    for(int i = 0; i < 4; i++)
#pragma unroll
      for(int j = 0; j < 4; j++) C[i][j] = f32x4{0.f,0.f,0.f,0.f};
#pragma unroll
    for(int ks = 0; ks < 2; ks++)
#pragma unroll
      for(int i = 0; i < 4; i++)
#pragma unroll
        for(int j = 0; j < 4; j++)
          C[i][j] = mfma_bf16(Aa[ks][i], Bb[ks][j], C[i][j]);
    write_CT_lds(zones + 7*4096, lane, C);

    // step B: D2 = rho_l * U   (SA = rho_l, SB = U^T stored)
#pragma unroll
    for(int ks = 0; ks < 2; ks++)
#pragma unroll
      for(int t = 0; t < 4; t++){
        Aa[ks][t] = lds_frag(zones + 6*4096, t*16 + m16, ks*32 + q*8);
        Bb[ks][t] = lds_frag(zones + 7*4096, t*16 + m16, ks*32 + q*8);
      }
#pragma unroll
    for(int i = 0; i < 4; i++)
#pragma unroll
      for(int j = 0; j < 4; j++) C[i][j] = f32x4{0.f,0.f,0.f,0.f};
#pragma unroll
    for(int ks = 0; ks < 2; ks++)
#pragma unroll
      for(int i = 0; i < 4; i++)
#pragma unroll
        for(int j = 0; j < 4; j++)
          C[i][j] = mfma_bf16(Aa[ks][i], Bb[ks][j], C[i][j]);

    // t1 = sum_ij D2_ij * M_ij  (elementwise with M from Pr, scalar u16 reads)
    float part = 0.f;
#pragma unroll
    for(int i = 0; i < 4; i++)
#pragma unroll
      for(int j = 0; j < 4; j++)
#pragma unroll
        for(int t = 0; t < 4; t++){
          int r = i*16 + q*4 + t, c = j*16 + m16;
          part += C[i][j][t] * bf2f(Pr[swz(r, c)]);
        }
    for(int off = 32; off; off >>= 1) part += __shfl_xor(part, off, 64);
    if(lane == 0){
      double t1  = (double)part;
      double lam = (double)(*mu_p);
      double S   = (double)(*S_p) + exps[0] + exps[1] + exps[2] + exps[3];
      double logp = 16384.0*log2(lam) - 2.0*S - log2(t1);
      outp[0] = (float)logp;
    }
  }
}

// ---------- launch ----------
extern "C" void kernel_launch(void* const* d_in, const int* in_sizes, int n_in,
                              void* d_out, int out_size, void* d_ws, size_t ws_size,
                              hipStream_t stream) {
  const float* K  = (const float*)d_in[0];   // (8,64,64) fp32
  const int* seq  = (const int*)d_in[1];     // (16384,) int32
  char* ws = (char*)d_ws;
  u16*   Kbf    = (u16*)(ws);                  // 65536
  u16*   KTbf   = (u16*)(ws + 65536);          // 65536
  float* rho_r  = (float*)(ws + 131072);       // 16384
  float* rho_l  = (float*)(ws + 147456);       // 16384
  int*   S_acc  = (int*)(ws + 163840);
  float* mu_acc = (float*)(ws + 163844);
  u16*   N1     = (u16*)(ws + 164352);         // 1024 * 8KB
  u16*   N2     = (u16*)(ws + 8552960);        // 64 * 8KB

  k_setup <<<128, 256, 0, stream>>>(K, Kbf, KTbf, S_acc, mu_acc);
  k_main  <<<130, 512, 0, stream>>>(Kbf, KTbf, seq, rho_r, rho_l, N1, S_acc);
  k_mid   <<<48,  256, 0, stream>>>(N1, N2, S_acc, K, rho_l, mu_acc);
  k_tail  <<<1,   256, 0, stream>>>(N2, rho_r, rho_l, mu_acc, S_acc, (float*)d_out);
}